// Round 3
// baseline (7537.698 us; speedup 1.0000x reference)
//
#include <hip/hip_runtime.h>
#include <math.h>
#include <stdint.h>

// Problem constants
constexpr int LL = 4096;   // seq len
constexpr int EE = 300;    // embedding dim
constexpr int HH = 256;    // per-direction hidden (H2)
constexpr int NGATE = 1024;// 4*HH
constexpr int TT = 16;     // tagset
constexpr float NEGV = -10000.0f;

typedef _Float16 v2h __attribute__((ext_vector_type(2)));
typedef _Float16 v8h __attribute__((ext_vector_type(8)));
typedef float v4f __attribute__((ext_vector_type(4)));

// Workspace layout (byte offsets)
constexpr size_t OFF_X    = 16384;
constexpr size_t OFF_ZX   = OFF_X    + (size_t)LL*EE*4;     // 2*L*1024 f32
constexpr size_t OFF_HALL = OFF_ZX   + (size_t)2*LL*NGATE*4;// 2*L*256 f32
constexpr size_t OFF_FE   = OFF_HALL + (size_t)2*LL*HH*4;   // L*16 f32

__device__ __forceinline__ v2h pack_h2(float x, float y) {
  return __builtin_bit_cast(v2h, __builtin_amdgcn_cvt_pkrtz(x, y));
}
__device__ __forceinline__ unsigned pack_u(float x, float y) {
  return __builtin_bit_cast(unsigned, __builtin_amdgcn_cvt_pkrtz(x, y));
}
__device__ __forceinline__ v2h u2h(unsigned u) {
  return __builtin_bit_cast(v2h, u);
}
__device__ __forceinline__ v8h make_v8h(v2h a, v2h b, v2h c, v2h d) {
  union { v2h p[4]; v8h v; } u; u.p[0]=a; u.p[1]=b; u.p[2]=c; u.p[3]=d; return u.v;
}

__device__ __forceinline__ float fsigmoid(float x) {
  return __builtin_amdgcn_rcpf(1.f + __expf(-x));
}
__device__ __forceinline__ float ftanh(float x) {
  return 1.f - 2.f * __builtin_amdgcn_rcpf(1.f + __expf(2.f * x));
}

template <int CTRL>
__device__ __forceinline__ int dpp_i(int v) {
  return __builtin_amdgcn_mov_dpp(v, CTRL, 0xF, 0xF, true);
}
template <int CTRL>
__device__ __forceinline__ float dpp_f(float v) {
  return __int_as_float(__builtin_amdgcn_mov_dpp(__float_as_int(v), CTRL, 0xF, 0xF, true));
}
__device__ __forceinline__ float bperm_f(int lane, float v) {
  return __int_as_float(__builtin_amdgcn_ds_bpermute(lane << 2, __float_as_int(v)));
}

// ---------------------------------------------------------------------------
// Kernel 1: embedding gather
// ---------------------------------------------------------------------------
__global__ void gather_x(const int* __restrict__ sent, const float* __restrict__ emb,
                         float* __restrict__ X) {
  const int i = blockIdx.x * blockDim.x + threadIdx.x;
  const int total = LL * (EE / 4);
  if (i >= total) return;
  const int row = i / (EE / 4), c4 = i % (EE / 4);
  const int v = sent[row];
  reinterpret_cast<float4*>(X)[(size_t)row * (EE / 4) + c4] =
      reinterpret_cast<const float4*>(emb + (size_t)v * EE)[c4];
}

// ---------------------------------------------------------------------------
// Kernel 2: input GEMM  Zx[dir][t][n] = X[t]·W_ih[n] + b[n]
// ---------------------------------------------------------------------------
__global__ __launch_bounds__(256) void input_gemm(
    const float* __restrict__ X, const float* __restrict__ w_f,
    const float* __restrict__ b_f, const float* __restrict__ w_b,
    const float* __restrict__ b_b, float* __restrict__ ZX) {
  const int dir = blockIdx.z;
  const float* __restrict__ W  = dir ? w_b : w_f;
  const float* __restrict__ Bv = dir ? b_b : b_f;
  float* __restrict__ Z = ZX + (size_t)dir * LL * NGATE;
  __shared__ float As[32][68];
  __shared__ float Bs[32][68];
  const int m0 = blockIdx.y * 64, n0 = blockIdx.x * 64;
  const int t = threadIdx.x;
  const int tx = t & 15, ty = t >> 4;
  float acc[4][4] = {};
  for (int k0 = 0; k0 < EE; k0 += 32) {
#pragma unroll
    for (int r = 0; r < 2; ++r) {
      const int idx = t + r * 256;
      const int row = idx >> 3;
      const int kk4 = (idx & 7) << 2;
      const int k = k0 + kk4;
      float4 va = make_float4(0.f, 0.f, 0.f, 0.f), vb = va;
      if (k < EE) {
        va = *reinterpret_cast<const float4*>(X + (size_t)(m0 + row) * EE + k);
        vb = *reinterpret_cast<const float4*>(W + (size_t)(n0 + row) * EE + k);
      }
      As[kk4 + 0][row] = va.x; As[kk4 + 1][row] = va.y;
      As[kk4 + 2][row] = va.z; As[kk4 + 3][row] = va.w;
      Bs[kk4 + 0][row] = vb.x; Bs[kk4 + 1][row] = vb.y;
      Bs[kk4 + 2][row] = vb.z; Bs[kk4 + 3][row] = vb.w;
    }
    __syncthreads();
    const int kmax = (EE - k0 < 32) ? (EE - k0) : 32;
    for (int k = 0; k < kmax; ++k) {
      const float4 av = *reinterpret_cast<const float4*>(&As[k][ty << 2]);
      const float4 bv = *reinterpret_cast<const float4*>(&Bs[k][tx << 2]);
      acc[0][0] += av.x * bv.x; acc[0][1] += av.x * bv.y; acc[0][2] += av.x * bv.z; acc[0][3] += av.x * bv.w;
      acc[1][0] += av.y * bv.x; acc[1][1] += av.y * bv.y; acc[1][2] += av.y * bv.z; acc[1][3] += av.y * bv.w;
      acc[2][0] += av.z * bv.x; acc[2][1] += av.z * bv.y; acc[2][2] += av.z * bv.z; acc[2][3] += av.z * bv.w;
      acc[3][0] += av.w * bv.x; acc[3][1] += av.w * bv.y; acc[3][2] += av.w * bv.z; acc[3][3] += av.w * bv.w;
    }
    __syncthreads();
  }
#pragma unroll
  for (int i = 0; i < 4; ++i)
#pragma unroll
    for (int j = 0; j < 4; ++j) {
      const int m = m0 + (ty << 2) + i, n = n0 + (tx << 2) + j;
      Z[(size_t)m * NGATE + n] = acc[i][j] + Bv[n];
    }
}

// ---------------------------------------------------------------------------
// Kernel 3: persistent bidirectional LSTM recurrence — one WG per direction,
// HYBRID matvec: VALU fdot2 + MFMA, both pipes concurrently (m114).
//
// R2 post-mortem: all-MFMA is pipe-bound at ~2480 cy/step because a matvec
// wastes 15/16 of each 16x16x32 MFMA (M=1). Costs per output n (K=256):
//   VALU v_dot2_f32_f16: 4 cy/SIMD (no waste)   MFMA: 9.7 cy/SIMD (16x waste)
// Register file (512 KB/CU) can hold only ~384 KB of the 512 KB f16 W_hh,
// so 128 KB/step must stream from LDS (~1200 cy @ ~110 B/cy) — that stream,
// the MFMA pipe (1244 cy), and the VALU pipe (~600 cy) all overlap.
//
// Partition of n (gate*256+unit):
//  [0,512)    VALU, weights in 128 arch VGPRs/thread. R1-verified layout:
//             thread (rq=t>>2, kq=t&3) owns rows rq+128j (j=0..3), k-slice
//             [64kq,64kq+64) as 32 consecutive (2p,2p+1) f16 pairs; partial
//             sums quad-reduced with 0xB1/0x4E DPP butterfly.
//  [512,768)  MFMA, B-frags register-resident (16 frags/thread, AGPR-legal).
//  [768,1024) MFMA, B-frags streamed from LDS (128 KB, b128, self-indexed).
// MFMA A-frag = h replicated across rows (R2-verified layout); C/D read uses
// col=lane&15 only. Arch-class demand ~170 << 256 so no R1 AGPR-stash risk.
// ---------------------------------------------------------------------------
__global__ __launch_bounds__(512) __attribute__((amdgpu_waves_per_eu(2, 2)))
void recurrence(
    const float* __restrict__ whh_f, const float* __restrict__ whh_b,
    const float* __restrict__ h0, const float* __restrict__ c0,
    const float* __restrict__ ZX, float* __restrict__ HALL) {
  const int dir = blockIdx.x;
  const int t = threadIdx.x;
  const int w = t >> 6;            // wave 0..7
  const int l = t & 63;
  const int lcol = l & 15;
  const int lq = l >> 4;           // quadrant 0..3
  const int rq = t >> 2;           // 0..127 (VALU row group)
  const int kq = t & 3;            // VALU k-quarter
  const float* __restrict__ Whh = dir ? whh_b : whh_f;
  const float* __restrict__ Z = ZX + (size_t)dir * LL * NGATE;
  float* __restrict__ Hall = HALL + (size_t)dir * LL * HH;

  __shared__ uint4 WL[8 * 16 * 64];              // 128 KB: LDS-resident B-frags
  __shared__ float zbuf[NGATE];                  // 4 KB
  __shared__ __align__(16) unsigned h16u[2 * 128]; // packed f16 h, parity dbuf

  // ---- preamble 1: VALU weights (n in [0,512)) -> 128 arch VGPRs ---------
  // wv[j][p] = (W[rq+128j][64kq+2p], W[rq+128j][64kq+2p+1])
  v2h wv[4][32];
#pragma unroll
  for (int j = 0; j < 4; ++j) {
    const float* wr = Whh + (size_t)(rq + (j << 7)) * HH + (kq << 6);
#pragma unroll
    for (int i = 0; i < 8; ++i) {
      const float4 x = *reinterpret_cast<const float4*>(wr + 8 * i);
      const float4 y = *reinterpret_cast<const float4*>(wr + 8 * i + 4);
      wv[j][4 * i + 0] = pack_h2(x.x, x.y);
      wv[j][4 * i + 1] = pack_h2(x.z, x.w);
      wv[j][4 * i + 2] = pack_h2(y.x, y.y);
      wv[j][4 * i + 3] = pack_h2(y.z, y.w);
    }
  }

  // ---- preamble 2: MFMA reg B-frags (n in [512,768)) ---------------------
  v8h bfr[16];
#pragma unroll
  for (int kc = 0; kc < 8; ++kc)
#pragma unroll
    for (int tn = 0; tn < 2; ++tn) {
      const int n = 512 + (w << 5) + (tn << 4) + lcol;
      const float* wp = Whh + (size_t)n * HH + (kc << 5) + (lq << 3);
      const float4 a4 = *reinterpret_cast<const float4*>(wp);
      const float4 b4 = *reinterpret_cast<const float4*>(wp + 4);
      bfr[2 * kc + tn] = make_v8h(pack_h2(a4.x, a4.y), pack_h2(a4.z, a4.w),
                                  pack_h2(b4.x, b4.y), pack_h2(b4.z, b4.w));
    }

  // ---- preamble 3: MFMA LDS B-frags (n in [768,1024)) --------------------
#pragma unroll
  for (int kc = 0; kc < 8; ++kc)
#pragma unroll
    for (int tn = 0; tn < 2; ++tn) {
      const int n = 768 + (w << 5) + (tn << 4) + lcol;
      const float* wp = Whh + (size_t)n * HH + (kc << 5) + (lq << 3);
      const float4 a4 = *reinterpret_cast<const float4*>(wp);
      const float4 b4 = *reinterpret_cast<const float4*>(wp + 4);
      uint4 p;
      p.x = pack_u(a4.x, a4.y); p.y = pack_u(a4.z, a4.w);
      p.z = pack_u(b4.x, b4.y); p.w = pack_u(b4.z, b4.w);
      WL[((w << 4) + 2 * kc + tn) * 64 + l] = p;
    }

  // ---- state init --------------------------------------------------------
  float c_reg = 0.f;
  if (t < 256) c_reg = c0[dir * HH + t];
  if (t < 128)
    h16u[t] = pack_u(h0[dir * HH + 2 * t], h0[dir * HH + 2 * t + 1]);

  float zx0 = 0.f, zx1 = 0.f, zx2 = 0.f, zx3 = 0.f;
  if (t < 256) {
    const int trow0 = dir ? (LL - 1) : 0;
    const float* zp = Z + (size_t)trow0 * NGATE + t;
    zx0 = zp[0]; zx1 = zp[HH]; zx2 = zp[2 * HH]; zx3 = zp[3 * HH];
  }
  __syncthreads();

  for (int s = 0; s < LL; ++s) {
    const int par = s & 1;
    // prefetch next step's Zx (hides under the matvec)
    float nzx0 = 0.f, nzx1 = 0.f, nzx2 = 0.f, nzx3 = 0.f;
    if (t < 256 && s + 1 < LL) {
      const int trow = dir ? (LL - 2 - s) : (s + 1);
      const float* zp = Z + (size_t)trow * NGATE + t;
      nzx0 = zp[0]; nzx1 = zp[HH]; nzx2 = zp[2 * HH]; nzx3 = zp[3 * HH];
    }

    const uint4* hq = reinterpret_cast<const uint4*>(&h16u[par << 7]);

    // ---- VALU part: rows rq+128j, k-slice [64kq, 64kq+64) ----------------
    float a0 = 0.f, a1 = 0.f, a2 = 0.f, a3 = 0.f;
#pragma unroll
    for (int i = 0; i < 8; ++i) {
      const uint4 hv = hq[(kq << 3) + i];
      const v2h hx = u2h(hv.x), hy = u2h(hv.y), hz = u2h(hv.z), hw = u2h(hv.w);
      a0 = __builtin_amdgcn_fdot2(wv[0][4*i+0], hx, a0, false);
      a1 = __builtin_amdgcn_fdot2(wv[1][4*i+0], hx, a1, false);
      a2 = __builtin_amdgcn_fdot2(wv[2][4*i+0], hx, a2, false);
      a3 = __builtin_amdgcn_fdot2(wv[3][4*i+0], hx, a3, false);
      a0 = __builtin_amdgcn_fdot2(wv[0][4*i+1], hy, a0, false);
      a1 = __builtin_amdgcn_fdot2(wv[1][4*i+1], hy, a1, false);
      a2 = __builtin_amdgcn_fdot2(wv[2][4*i+1], hy, a2, false);
      a3 = __builtin_amdgcn_fdot2(wv[3][4*i+1], hy, a3, false);
      a0 = __builtin_amdgcn_fdot2(wv[0][4*i+2], hz, a0, false);
      a1 = __builtin_amdgcn_fdot2(wv[1][4*i+2], hz, a1, false);
      a2 = __builtin_amdgcn_fdot2(wv[2][4*i+2], hz, a2, false);
      a3 = __builtin_amdgcn_fdot2(wv[3][4*i+2], hz, a3, false);
      a0 = __builtin_amdgcn_fdot2(wv[0][4*i+3], hw, a0, false);
      a1 = __builtin_amdgcn_fdot2(wv[1][4*i+3], hw, a1, false);
      a2 = __builtin_amdgcn_fdot2(wv[2][4*i+3], hw, a2, false);
      a3 = __builtin_amdgcn_fdot2(wv[3][4*i+3], hw, a3, false);
    }
    // quad butterfly: sum the 4 k-quarters (R1-verified pattern)
    a0 += dpp_f<0xB1>(a0); a0 += dpp_f<0x4E>(a0);
    a1 += dpp_f<0xB1>(a1); a1 += dpp_f<0x4E>(a1);
    a2 += dpp_f<0xB1>(a2); a2 += dpp_f<0x4E>(a2);
    a3 += dpp_f<0xB1>(a3); a3 += dpp_f<0x4E>(a3);

    // ---- MFMA part: n in [512,1024) --------------------------------------
    v4f acc0 = {0.f,0.f,0.f,0.f}, acc1 = {0.f,0.f,0.f,0.f};
    v4f acc2 = {0.f,0.f,0.f,0.f}, acc3 = {0.f,0.f,0.f,0.f};
#pragma unroll
    for (int kc = 0; kc < 8; ++kc) {
      const uint4 ahv = hq[(kc << 2) + lq];
      const v8h ah = __builtin_bit_cast(v8h, ahv);
      acc0 = __builtin_amdgcn_mfma_f32_16x16x32_f16(ah, bfr[2*kc+0], acc0, 0, 0, 0);
      acc1 = __builtin_amdgcn_mfma_f32_16x16x32_f16(ah, bfr[2*kc+1], acc1, 0, 0, 0);
      const uint4 w0 = WL[((w << 4) + 2*kc + 0) * 64 + l];
      const uint4 w1 = WL[((w << 4) + 2*kc + 1) * 64 + l];
      acc2 = __builtin_amdgcn_mfma_f32_16x16x32_f16(ah, __builtin_bit_cast(v8h, w0), acc2, 0, 0, 0);
      acc3 = __builtin_amdgcn_mfma_f32_16x16x32_f16(ah, __builtin_bit_cast(v8h, w1), acc3, 0, 0, 0);
    }

    // ---- z writes --------------------------------------------------------
    if (kq == 0) {
      zbuf[rq]       = a0;
      zbuf[rq + 128] = a1;
      zbuf[rq + 256] = a2;
      zbuf[rq + 384] = a3;
    }
    if (lq == 0) {
      zbuf[512 + (w << 5) + lcol]      = acc0[0];
      zbuf[512 + (w << 5) + 16 + lcol] = acc1[0];
      zbuf[768 + (w << 5) + lcol]      = acc2[0];
      zbuf[768 + (w << 5) + 16 + lcol] = acc3[0];
    }
    __syncthreads();

    // ---- gate phase (unit u = t, threads 0..255) -------------------------
    if (t < 256) {
      const float z0 = zx0 + zbuf[t];
      const float z1 = zx1 + zbuf[256 + t];
      const float z2 = zx2 + zbuf[512 + t];
      const float z3 = zx3 + zbuf[768 + t];
      const float ig = fsigmoid(z0);
      const float fg = fsigmoid(z1);
      const float gg = ftanh(z2);
      const float og = fsigmoid(z3);
      c_reg = fg * c_reg + ig * gg;
      const float hval = og * ftanh(c_reg);
      const int trow = dir ? (LL - 1 - s) : s;
      Hall[(size_t)trow * HH + t] = hval;
      const float hnb = dpp_f<0xB1>(hval);   // neighbor (t^1) within wave
      if ((t & 1) == 0)
        h16u[((par ^ 1) << 7) + (t >> 1)] = pack_u(hval, hnb);
    }
    __syncthreads();
    zx0 = nzx0; zx1 = nzx1; zx2 = nzx2; zx3 = nzx3;
  }
}

// ---------------------------------------------------------------------------
// Kernel 4: feats
// ---------------------------------------------------------------------------
__global__ __launch_bounds__(256) void feats_gemm(
    const float* __restrict__ HALL, const float* __restrict__ Wout,
    const float* __restrict__ bout, float* __restrict__ FE) {
  __shared__ float Wl[16][516];
  const int t = threadIdx.x;
  for (int i = t; i < 16 * 512; i += 256) Wl[i >> 9][i & 511] = Wout[i];
  __syncthreads();
  const int row = blockIdx.x * 16 + (t >> 4);
  const int j = t & 15;
  const float* hf = HALL + (size_t)row * HH;
  const float* hb = HALL + (size_t)LL * HH + (size_t)row * HH;
  float acc = bout[j];
  for (int k = 0; k < HH; k += 4) {
    const float4 a = *reinterpret_cast<const float4*>(hf + k);
    const float4 wa = *reinterpret_cast<const float4*>(&Wl[j][k]);
    acc += a.x * wa.x + a.y * wa.y + a.z * wa.z + a.w * wa.w;
    const float4 b2 = *reinterpret_cast<const float4*>(hb + k);
    const float4 wb = *reinterpret_cast<const float4*>(&Wl[j][256 + k]);
    acc += b2.x * wb.x + b2.y * wb.y + b2.z * wb.z + b2.w * wb.w;
  }
  FE[(size_t)row * TT + j] = acc;
}

// ---------------------------------------------------------------------------
// Kernel 5: Viterbi (unchanged)
// ---------------------------------------------------------------------------
__global__ __launch_bounds__(1024) void viterbi(
    const float* __restrict__ FE, const float* __restrict__ trans,
    float* __restrict__ out) {
  __shared__ unsigned char bp8[LL * TT];
  __shared__ unsigned char xc[64 * 16];
  __shared__ unsigned char entry[64];
  __shared__ int sbest;
  const int t = threadIdx.x;

  if (t < 64) {
    const int n = t >> 2, pg = t & 3;
    const float tr0 = trans[n * 16 + (pg << 2) + 0];
    const float tr1 = trans[n * 16 + (pg << 2) + 1];
    const float tr2 = trans[n * 16 + (pg << 2) + 2];
    const float tr3 = trans[n * 16 + (pg << 2) + 3];
    float fvp0 = ((pg << 2) + 0 == 14) ? 0.f : NEGV;
    float fvp1 = ((pg << 2) + 1 == 14) ? 0.f : NEGV;
    float fvp2 = ((pg << 2) + 2 == 14) ? 0.f : NEGV;
    float fvp3 = ((pg << 2) + 3 == 14) ? 0.f : NEGV;

    auto step = [&](int s, float feat) {
      float bv = fvp0 + tr0; int bi = (pg << 2);
      float c;
      c = fvp1 + tr1; if (c > bv) { bv = c; bi = (pg << 2) + 1; }
      c = fvp2 + tr2; if (c > bv) { bv = c; bi = (pg << 2) + 2; }
      c = fvp3 + tr3; if (c > bv) { bv = c; bi = (pg << 2) + 3; }
      float pv = dpp_f<0xB1>(bv); int pi = dpp_i<0xB1>(bi);
      if (pv > bv || (pv == bv && pi < bi)) { bv = pv; bi = pi; }
      pv = dpp_f<0x4E>(bv); pi = dpp_i<0x4E>(bi);
      if (pv > bv || (pv == bv && pi < bi)) { bv = pv; bi = pi; }
      if (pg == 0) bp8[(s << 4) + n] = (unsigned char)bi;
      const float fvn = bv + feat;
      fvp0 = bperm_f((pg << 4) + 0,  fvn);
      fvp1 = bperm_f((pg << 4) + 4,  fvn);
      fvp2 = bperm_f((pg << 4) + 8,  fvn);
      fvp3 = bperm_f((pg << 4) + 12, fvn);
    };

    float fb0 = FE[(0 << 4) + n], fb1 = FE[(1 << 4) + n];
    float fb2 = FE[(2 << 4) + n], fb3 = FE[(3 << 4) + n];
    for (int s = 0; s < LL; s += 4) {
      step(s + 0, fb0); fb0 = (s + 4 < LL) ? FE[((s + 4) << 4) + n] : 0.f;
      step(s + 1, fb1); fb1 = (s + 5 < LL) ? FE[((s + 5) << 4) + n] : 0.f;
      step(s + 2, fb2); fb2 = (s + 6 < LL) ? FE[((s + 6) << 4) + n] : 0.f;
      step(s + 3, fb3); fb3 = (s + 7 < LL) ? FE[((s + 7) << 4) + n] : 0.f;
    }

    const float tt0 = trans[240 + (pg << 2) + 0];
    const float tt1 = trans[240 + (pg << 2) + 1];
    const float tt2 = trans[240 + (pg << 2) + 2];
    const float tt3 = trans[240 + (pg << 2) + 3];
    float bv = fvp0 + tt0; int bi = (pg << 2);
    float c;
    c = fvp1 + tt1; if (c > bv) { bv = c; bi = (pg << 2) + 1; }
    c = fvp2 + tt2; if (c > bv) { bv = c; bi = (pg << 2) + 2; }
    c = fvp3 + tt3; if (c > bv) { bv = c; bi = (pg << 2) + 3; }
    float pv = dpp_f<0xB1>(bv); int pi = dpp_i<0xB1>(bi);
    if (pv > bv || (pv == bv && pi < bi)) { bv = pv; bi = pi; }
    pv = dpp_f<0x4E>(bv); pi = dpp_i<0x4E>(bi);
    if (pv > bv || (pv == bv && pi < bi)) { bv = pv; bi = pi; }
    if (t == 0) { out[0] = bv; sbest = bi; }
  }
  __syncthreads();

  {
    const int c = t >> 4, e = t & 15;
    int tag = e;
#pragma unroll 1
    for (int i = 63; i >= 0; --i) tag = bp8[(((c << 6) + i) << 4) + tag];
    xc[(c << 4) + e] = (unsigned char)tag;
  }
  __syncthreads();
  if (t == 0) {
    int carry = sbest;
#pragma unroll 1
    for (int c = 63; c >= 0; --c) {
      entry[c] = (unsigned char)carry;
      carry = xc[(c << 4) + carry];
    }
  }
  __syncthreads();
  if (t < 64) {
    const int c = t;
    int tag = entry[c];
#pragma unroll 1
    for (int i = 63; i >= 0; --i) {
      const int s = (c << 6) + i;
      out[1 + s] = (float)tag;
      tag = bp8[(s << 4) + tag];
    }
  }
}

// ---------------------------------------------------------------------------
extern "C" void kernel_launch(void* const* d_in, const int* in_sizes, int n_in,
                              void* d_out, int out_size, void* d_ws, size_t ws_size,
                              hipStream_t stream) {
  const int*   sent = (const int*)d_in[0];
  const float* emb  = (const float*)d_in[1];
  const float* wihf = (const float*)d_in[2];
  const float* whhf = (const float*)d_in[3];
  const float* bf   = (const float*)d_in[4];
  const float* wihb = (const float*)d_in[5];
  const float* whhb = (const float*)d_in[6];
  const float* bb   = (const float*)d_in[7];
  const float* wout = (const float*)d_in[8];
  const float* bout = (const float*)d_in[9];
  const float* trans= (const float*)d_in[10];
  const float* h0   = (const float*)d_in[11];
  const float* c0   = (const float*)d_in[12];
  float* out = (float*)d_out;
  char* ws = (char*)d_ws;

  float* X    = (float*)(ws + OFF_X);
  float* ZX   = (float*)(ws + OFF_ZX);
  float* HALL = (float*)(ws + OFF_HALL);
  float* FE   = (float*)(ws + OFF_FE);

  gather_x<<<(LL * (EE / 4) + 255) / 256, 256, 0, stream>>>(sent, emb, X);
  input_gemm<<<dim3(16, 64, 2), 256, 0, stream>>>(X, wihf, bf, wihb, bb, ZX);
  recurrence<<<2, 512, 0, stream>>>(whhf, whhb, h0, c0, ZX, HALL);
  feats_gemm<<<LL / 16, 256, 0, stream>>>(HALL, wout, bout, FE);
  viterbi<<<1, 1024, 0, stream>>>(FE, trans, out);
}